// Round 4
// baseline (164.648 us; speedup 1.0000x reference)
//
#include <hip/hip_runtime.h>
#include <math.h>

#define TAU_INV 2.0f   // 1/0.5
#define EPS 1e-8f

// DPP cross-lane add on the VALU pipe (no DS/shuffle-pipe traffic).
// CTRL: 0xB1 = quad_perm(1,0,3,2) -> xor1; 0x4E = quad_perm(2,3,0,1) -> xor2;
// 0x141 = row_half_mirror (l <-> 7-l within each 8-lane half-row) -> cross-quad.
template<int CTRL>
__device__ __forceinline__ float dpp_add(float x) {
    int y = __builtin_amdgcn_update_dpp(0, __float_as_int(x), CTRL, 0xF, 0xF, true);
    return x + __int_as_float(y);
}

// 8 lanes per row (D=128 = 8 lanes x 4 float4). Each global_load_dwordx4
// covers a full 128B line per row -> perfect coalescing. Row reduction is
// 3 DPP adds per value -- R3 was DS-pipe bound (25 ds_bpermute per 2 rows);
// this has ZERO DS ops in the hot loop.
__global__ __launch_bounds__(256) void contrast_partial(
    const float* __restrict__ xr, const float* __restrict__ xp,
    const float* __restrict__ xn, float* __restrict__ partials, int N)
{
    const int l8    = threadIdx.x & 7;       // lane within row-group
    const int rgrp  = threadIdx.x >> 3;      // 0..31 row slot in block
    const int rstep = gridDim.x * 32;        // rows per grid pass

    float acc = 0.0f;                        // valid on l8==0 lanes
    for (int row = blockIdx.x * 32 + rgrp; row < N; row += rstep) {
        const size_t base = (size_t)row * 128;
        const float4* r4 = (const float4*)(xr + base);
        const float4* p4 = (const float4*)(xp + base);
        const float4* n4 = (const float4*)(xn + base);

        float s_rp = 0.f, s_rn = 0.f, s_rr = 0.f, s_pp = 0.f, s_nn = 0.f;
        #pragma unroll
        for (int j = 0; j < 4; ++j) {
            const float4 r = r4[j * 8 + l8];
            const float4 p = p4[j * 8 + l8];
            const float4 n = n4[j * 8 + l8];
            s_rp += r.x*p.x + r.y*p.y + r.z*p.z + r.w*p.w;
            s_rn += r.x*n.x + r.y*n.y + r.z*n.z + r.w*n.w;
            s_rr += r.x*r.x + r.y*r.y + r.z*r.z + r.w*r.w;
            s_pp += p.x*p.x + p.y*p.y + p.z*p.z + p.w*p.w;
            s_nn += n.x*n.x + n.y*n.y + n.z*n.z + n.w*n.w;
        }

        // 8-lane sum entirely in DPP (VALU rate): after the three steps all
        // 8 lanes hold the row total.
        s_rp = dpp_add<0xB1>(s_rp); s_rp = dpp_add<0x4E>(s_rp); s_rp = dpp_add<0x141>(s_rp);
        s_rn = dpp_add<0xB1>(s_rn); s_rn = dpp_add<0x4E>(s_rn); s_rn = dpp_add<0x141>(s_rn);
        s_rr = dpp_add<0xB1>(s_rr); s_rr = dpp_add<0x4E>(s_rr); s_rr = dpp_add<0x141>(s_rr);
        s_pp = dpp_add<0xB1>(s_pp); s_pp = dpp_add<0x4E>(s_pp); s_pp = dpp_add<0x141>(s_pp);
        s_nn = dpp_add<0xB1>(s_nn); s_nn = dpp_add<0x4E>(s_nn); s_nn = dpp_add<0x141>(s_nn);

        const float inv_r = rsqrtf(s_rr);
        const float pos = __expf(s_rp * inv_r * rsqrtf(s_pp) * TAU_INV);
        const float neg = __expf(s_rn * inv_r * rsqrtf(s_nn) * TAU_INV);
        acc += pos / (neg + EPS);            // replicated on all 8 lanes
    }

    // Block sum: one LDS slot per row-slot (take l8==0 copy -> no overcount).
    __shared__ float part[32];
    if (l8 == 0) part[rgrp] = acc;
    __syncthreads();
    if (threadIdx.x == 0) {
        float t = 0.f;
        #pragma unroll
        for (int i = 0; i < 32; ++i) t += part[i];
        partials[blockIdx.x] = t;            // plain store, deterministic
    }
}

// Single block: reduce nblk partials (all freshly written), write -log(sum).
__global__ __launch_bounds__(1024) void contrast_final(
    const float* __restrict__ partials, float* __restrict__ out, int nblk)
{
    float s = 0.0f;
    for (int i = threadIdx.x; i < nblk; i += 1024)
        s += partials[i];

    #pragma unroll
    for (int off = 32; off > 0; off >>= 1)
        s += __shfl_xor(s, off);             // one-time wave64 butterfly

    __shared__ float w[16];
    if ((threadIdx.x & 63) == 0) w[threadIdx.x >> 6] = s;
    __syncthreads();
    if (threadIdx.x == 0) {
        float t = 0.f;
        #pragma unroll
        for (int i = 0; i < 16; ++i) t += w[i];
        out[0] = -logf(t);
    }
}

extern "C" void kernel_launch(void* const* d_in, const int* in_sizes, int n_in,
                              void* d_out, int out_size, void* d_ws, size_t ws_size,
                              hipStream_t stream) {
    const float* xr = (const float*)d_in[0];
    const float* xp = (const float*)d_in[1];
    const float* xn = (const float*)d_in[2];
    float* out      = (float*)d_out;
    float* partials = (float*)d_ws;

    const int N = in_sizes[0] / 128;         // 100000

    // 32 rows per 256-thread block -> 3125 blocks exactly covers N.
    int nblk = (N + 31) / 32;
    const int cap = (int)(ws_size / sizeof(float));
    if (nblk > cap) nblk = cap;              // grid-stride loop keeps it correct

    contrast_partial<<<nblk, 256, 0, stream>>>(xr, xp, xn, partials, N);
    contrast_final<<<1, 1024, 0, stream>>>(partials, out, nblk);
}

// Round 6
// 151.224 us; speedup vs baseline: 1.0888x; 1.0888x over previous
//
#include <hip/hip_runtime.h>
#include <math.h>

#define TAU_INV 2.0f   // 1/0.5
#define EPS 1e-8f

// Native clang vector type -- __builtin_nontemporal_load requires a pointer
// to scalar/vector-of-scalar, not HIP's float4 struct.
typedef float vfloat4 __attribute__((ext_vector_type(4)));

// DPP cross-lane add on the VALU pipe (no DS/shuffle-pipe traffic).
template<int CTRL>
__device__ __forceinline__ float dpp_add(float x) {
    int y = __builtin_amdgcn_update_dpp(0, __float_as_int(x), CTRL, 0xF, 0xF, true);
    return x + __int_as_float(y);
}

__device__ __forceinline__ vfloat4 nt_load4(const float* p) {
    // Non-temporal: probe caches but don't allocate -> don't evict the
    // harness's dirty restore lines (theory: hidden writeback contention).
    return __builtin_nontemporal_load((const vfloat4*)p);
}

// 8 lanes per row (D=128 = 8 lanes x 4 float4), zero DS ops in hot loop.
__global__ __launch_bounds__(256) void contrast_partial(
    const float* __restrict__ xr, const float* __restrict__ xp,
    const float* __restrict__ xn, float* __restrict__ partials, int N)
{
    const int l8    = threadIdx.x & 7;       // lane within row-group
    const int rgrp  = threadIdx.x >> 3;      // 0..31 row slot in block
    const int rstep = gridDim.x * 32;        // rows per grid pass

    float acc = 0.0f;
    for (int row = blockIdx.x * 32 + rgrp; row < N; row += rstep) {
        const size_t base = (size_t)row * 128;

        float s_rp = 0.f, s_rn = 0.f, s_rr = 0.f, s_pp = 0.f, s_nn = 0.f;
        #pragma unroll
        for (int j = 0; j < 4; ++j) {
            const size_t off = base + (size_t)(j * 8 + l8) * 4;
            const vfloat4 r = nt_load4(xr + off);
            const vfloat4 p = nt_load4(xp + off);
            const vfloat4 n = nt_load4(xn + off);
            s_rp += r.x*p.x + r.y*p.y + r.z*p.z + r.w*p.w;
            s_rn += r.x*n.x + r.y*n.y + r.z*n.z + r.w*n.w;
            s_rr += r.x*r.x + r.y*r.y + r.z*r.z + r.w*r.w;
            s_pp += p.x*p.x + p.y*p.y + p.z*p.z + p.w*p.w;
            s_nn += n.x*n.x + n.y*n.y + n.z*n.z + n.w*n.w;
        }

        // 8-lane sum on the VALU pipe; all 8 lanes end with the row total.
        s_rp = dpp_add<0xB1>(s_rp); s_rp = dpp_add<0x4E>(s_rp); s_rp = dpp_add<0x141>(s_rp);
        s_rn = dpp_add<0xB1>(s_rn); s_rn = dpp_add<0x4E>(s_rn); s_rn = dpp_add<0x141>(s_rn);
        s_rr = dpp_add<0xB1>(s_rr); s_rr = dpp_add<0x4E>(s_rr); s_rr = dpp_add<0x141>(s_rr);
        s_pp = dpp_add<0xB1>(s_pp); s_pp = dpp_add<0x4E>(s_pp); s_pp = dpp_add<0x141>(s_pp);
        s_nn = dpp_add<0xB1>(s_nn); s_nn = dpp_add<0x4E>(s_nn); s_nn = dpp_add<0x141>(s_nn);

        const float inv_r = rsqrtf(s_rr);
        const float pos = __expf(s_rp * inv_r * rsqrtf(s_pp) * TAU_INV);
        const float neg = __expf(s_rn * inv_r * rsqrtf(s_nn) * TAU_INV);
        acc += pos / (neg + EPS);            // replicated on all 8 lanes
    }

    __shared__ float part[32];
    if (l8 == 0) part[rgrp] = acc;
    __syncthreads();
    if (threadIdx.x == 0) {
        float t = 0.f;
        #pragma unroll
        for (int i = 0; i < 32; ++i) t += part[i];
        partials[blockIdx.x] = t;            // plain store, deterministic
    }
}

// Single block: reduce nblk partials (all freshly written), write -log(sum).
__global__ __launch_bounds__(1024) void contrast_final(
    const float* __restrict__ partials, float* __restrict__ out, int nblk)
{
    float s = 0.0f;
    for (int i = threadIdx.x; i < nblk; i += 1024)
        s += partials[i];

    #pragma unroll
    for (int off = 32; off > 0; off >>= 1)
        s += __shfl_xor(s, off);             // one-time wave64 butterfly

    __shared__ float w[16];
    if ((threadIdx.x & 63) == 0) w[threadIdx.x >> 6] = s;
    __syncthreads();
    if (threadIdx.x == 0) {
        float t = 0.f;
        #pragma unroll
        for (int i = 0; i < 16; ++i) t += w[i];
        out[0] = -logf(t);
    }
}

extern "C" void kernel_launch(void* const* d_in, const int* in_sizes, int n_in,
                              void* d_out, int out_size, void* d_ws, size_t ws_size,
                              hipStream_t stream) {
    const float* xr = (const float*)d_in[0];
    const float* xp = (const float*)d_in[1];
    const float* xn = (const float*)d_in[2];
    float* out      = (float*)d_out;
    float* partials = (float*)d_ws;

    const int N = in_sizes[0] / 128;         // 100000

    int nblk = (N + 31) / 32;                // 3125: one row per 8-lane group
    const int cap = (int)(ws_size / sizeof(float));
    if (nblk > cap) nblk = cap;              // grid-stride keeps smaller grids correct

    contrast_partial<<<nblk, 256, 0, stream>>>(xr, xp, xn, partials, N);
    contrast_final<<<1, 1024, 0, stream>>>(partials, out, nblk);
}

// Round 7
// 150.422 us; speedup vs baseline: 1.0946x; 1.0053x over previous
//
#include <hip/hip_runtime.h>
#include <math.h>

#define TAU_INV 2.0f   // 1/0.5
#define EPS 1e-8f
#define NBLK 2048      // 2048 blk x 4 waves = 8192 waves = exact chip fill

// Native clang vector type -- __builtin_nontemporal_load requires a pointer
// to scalar/vector-of-scalar, not HIP's float4 struct.
typedef float vfloat4 __attribute__((ext_vector_type(4)));

// DPP cross-lane add on the VALU pipe (no DS/shuffle-pipe traffic).
template<int CTRL>
__device__ __forceinline__ float dpp_add(float x) {
    int y = __builtin_amdgcn_update_dpp(0, __float_as_int(x), CTRL, 0xF, 0xF, true);
    return x + __int_as_float(y);
}

__device__ __forceinline__ vfloat4 nt_load4(const float* p) {
    // Non-temporal (no-allocate): probe caches but don't evict the harness's
    // dirty restore/poison lines. Measured R6: kernel 52 -> ~39 us.
    return __builtin_nontemporal_load((const vfloat4*)p);
}

// 8 lanes per row (D=128 = 8 lanes x 4 float4), zero DS ops in hot loop.
// Grid-stride with exact-fill grid: every wave resident start-to-finish,
// loads of row i+1 overlap compute tail of row i.
__global__ __launch_bounds__(256) void contrast_partial(
    const float* __restrict__ xr, const float* __restrict__ xp,
    const float* __restrict__ xn, float* __restrict__ partials, int N)
{
    const int l8    = threadIdx.x & 7;       // lane within row-group
    const int rgrp  = threadIdx.x >> 3;      // 0..31 row slot in block
    const int rstep = gridDim.x * 32;        // rows per grid pass

    float acc = 0.0f;
    for (int row = blockIdx.x * 32 + rgrp; row < N; row += rstep) {
        const size_t base = (size_t)row * 128;

        float s_rp = 0.f, s_rn = 0.f, s_rr = 0.f, s_pp = 0.f, s_nn = 0.f;
        #pragma unroll
        for (int j = 0; j < 4; ++j) {
            const size_t off = base + (size_t)(j * 8 + l8) * 4;
            const vfloat4 r = nt_load4(xr + off);
            const vfloat4 p = nt_load4(xp + off);
            const vfloat4 n = nt_load4(xn + off);
            s_rp += r.x*p.x + r.y*p.y + r.z*p.z + r.w*p.w;
            s_rn += r.x*n.x + r.y*n.y + r.z*n.z + r.w*n.w;
            s_rr += r.x*r.x + r.y*r.y + r.z*r.z + r.w*r.w;
            s_pp += p.x*p.x + p.y*p.y + p.z*p.z + p.w*p.w;
            s_nn += n.x*n.x + n.y*n.y + n.z*n.z + n.w*n.w;
        }

        // 8-lane sum on the VALU pipe; all 8 lanes end with the row total.
        s_rp = dpp_add<0xB1>(s_rp); s_rp = dpp_add<0x4E>(s_rp); s_rp = dpp_add<0x141>(s_rp);
        s_rn = dpp_add<0xB1>(s_rn); s_rn = dpp_add<0x4E>(s_rn); s_rn = dpp_add<0x141>(s_rn);
        s_rr = dpp_add<0xB1>(s_rr); s_rr = dpp_add<0x4E>(s_rr); s_rr = dpp_add<0x141>(s_rr);
        s_pp = dpp_add<0xB1>(s_pp); s_pp = dpp_add<0x4E>(s_pp); s_pp = dpp_add<0x141>(s_pp);
        s_nn = dpp_add<0xB1>(s_nn); s_nn = dpp_add<0x4E>(s_nn); s_nn = dpp_add<0x141>(s_nn);

        const float inv_r = rsqrtf(s_rr);
        const float pos = __expf(s_rp * inv_r * rsqrtf(s_pp) * TAU_INV);
        const float neg = __expf(s_rn * inv_r * rsqrtf(s_nn) * TAU_INV);
        acc += pos / (neg + EPS);            // replicated on all 8 lanes
    }

    __shared__ float part[32];
    if (l8 == 0) part[rgrp] = acc;
    __syncthreads();
    if (threadIdx.x == 0) {
        float t = 0.f;
        #pragma unroll
        for (int i = 0; i < 32; ++i) t += part[i];
        partials[blockIdx.x] = t;            // plain store, deterministic
    }
}

// Single block: reduce nblk partials (all freshly written), write -log(sum).
__global__ __launch_bounds__(1024) void contrast_final(
    const float* __restrict__ partials, float* __restrict__ out, int nblk)
{
    float s = 0.0f;
    for (int i = threadIdx.x; i < nblk; i += 1024)
        s += partials[i];

    #pragma unroll
    for (int off = 32; off > 0; off >>= 1)
        s += __shfl_xor(s, off);             // one-time wave64 butterfly

    __shared__ float w[16];
    if ((threadIdx.x & 63) == 0) w[threadIdx.x >> 6] = s;
    __syncthreads();
    if (threadIdx.x == 0) {
        float t = 0.f;
        #pragma unroll
        for (int i = 0; i < 16; ++i) t += w[i];
        out[0] = -logf(t);
    }
}

extern "C" void kernel_launch(void* const* d_in, const int* in_sizes, int n_in,
                              void* d_out, int out_size, void* d_ws, size_t ws_size,
                              hipStream_t stream) {
    const float* xr = (const float*)d_in[0];
    const float* xp = (const float*)d_in[1];
    const float* xn = (const float*)d_in[2];
    float* out      = (float*)d_out;
    float* partials = (float*)d_ws;

    const int N = in_sizes[0] / 128;         // 100000

    int nblk = NBLK;                         // grid-stride covers all rows
    const int cap = (int)(ws_size / sizeof(float));
    if (nblk > cap) nblk = cap;

    contrast_partial<<<nblk, 256, 0, stream>>>(xr, xp, xn, partials, N);
    contrast_final<<<1, 1024, 0, stream>>>(partials, out, nblk);
}